// Round 1
// baseline (52.121 us; speedup 1.0000x reference)
//
#include <hip/hip_runtime.h>
#include <math.h>

#define NPTS 2048
#define THREADS 256

// ---------------- Kernel 1: per-batch weighted reduction ----------------
// Computes, per batch b, the 16 sums over n of:
//   [0]  w
//   [1..3]  w*src
//   [4..6]  w*tgt
//   [7..15] w*src_d*tgt_e (row-major d,e)
// where w is the thresholded (w<0.5 -> 0) UNNORMALIZED weight.
__global__ __launch_bounds__(THREADS) void wp_reduce_kernel(
    const float* __restrict__ src, const float* __restrict__ tgt,
    const float* __restrict__ w, float* __restrict__ ws)
{
    const int b = blockIdx.x;
    const int tid = threadIdx.x;
    const float* sp = src + (size_t)b * NPTS * 3;
    const float* tp = tgt + (size_t)b * NPTS * 3;
    const float* wp = w + (size_t)b * NPTS;

    float acc[16];
#pragma unroll
    for (int i = 0; i < 16; ++i) acc[i] = 0.f;

#pragma unroll
    for (int it = 0; it < NPTS / THREADS; ++it) {
        const int n = tid + it * THREADS;
        float wv = wp[n];
        wv = (wv < 0.5f) ? 0.f : wv;
        const float sx = sp[3 * n + 0];
        const float sy = sp[3 * n + 1];
        const float sz = sp[3 * n + 2];
        const float tx = tp[3 * n + 0];
        const float ty = tp[3 * n + 1];
        const float tz = tp[3 * n + 2];
        const float wsx = wv * sx, wsy = wv * sy, wsz = wv * sz;
        acc[0] += wv;
        acc[1] += wsx; acc[2] += wsy; acc[3] += wsz;
        acc[4] += wv * tx; acc[5] += wv * ty; acc[6] += wv * tz;
        acc[7]  += wsx * tx; acc[8]  += wsx * ty; acc[9]  += wsx * tz;
        acc[10] += wsy * tx; acc[11] += wsy * ty; acc[12] += wsy * tz;
        acc[13] += wsz * tx; acc[14] += wsz * ty; acc[15] += wsz * tz;
    }

    // 64-lane wave butterfly reduction of all 16 accumulators
#pragma unroll
    for (int off = 32; off >= 1; off >>= 1) {
#pragma unroll
        for (int i = 0; i < 16; ++i)
            acc[i] += __shfl_xor(acc[i], off, 64);
    }

    __shared__ float lds[4][16];
    const int wave = tid >> 6;
    const int lane = tid & 63;
    if (lane == 0) {
#pragma unroll
        for (int i = 0; i < 16; ++i) lds[wave][i] = acc[i];
    }
    __syncthreads();
    if (tid < 16) {
        const float v = lds[0][tid] + lds[1][tid] + lds[2][tid] + lds[3][tid];
        ws[(size_t)b * 16 + tid] = v;
    }
}

// ---------------- Kernel 2: per-batch 3x3 Kabsch (fp64 Jacobi SVD) ----------------

template <int P, int Q>
__device__ inline void jrot(double A[3][3], double V[3][3])
{
    const double apq = A[P][Q];
    if (fabs(apq) < 1e-300) return;
    const double theta = (A[Q][Q] - A[P][P]) / (2.0 * apq);
    const double t = ((theta >= 0.0) ? 1.0 : -1.0) /
                     (fabs(theta) + sqrt(theta * theta + 1.0));
    const double c = 1.0 / sqrt(t * t + 1.0);
    const double s = t * c;
#pragma unroll
    for (int k = 0; k < 3; ++k) {
        const double akp = A[k][P], akq = A[k][Q];
        A[k][P] = c * akp - s * akq;
        A[k][Q] = s * akp + c * akq;
    }
#pragma unroll
    for (int k = 0; k < 3; ++k) {
        const double apk = A[P][k], aqk = A[Q][k];
        A[P][k] = c * apk - s * aqk;
        A[Q][k] = s * apk + c * aqk;
    }
#pragma unroll
    for (int k = 0; k < 3; ++k) {
        const double vkp = V[k][P], vkq = V[k][Q];
        V[k][P] = c * vkp - s * vkq;
        V[k][Q] = s * vkp + c * vkq;
    }
}

__device__ inline void matvec3(const double H[3][3], const double v[3], double u[3])
{
#pragma unroll
    for (int i = 0; i < 3; ++i)
        u[i] = H[i][0] * v[0] + H[i][1] * v[1] + H[i][2] * v[2];
}

__device__ inline double dot3(const double a[3], const double b[3])
{
    return a[0] * b[0] + a[1] * b[1] + a[2] * b[2];
}

__device__ inline void cross3(const double a[3], const double b[3], double c[3])
{
    c[0] = a[1] * b[2] - a[2] * b[1];
    c[1] = a[2] * b[0] - a[0] * b[2];
    c[2] = a[0] * b[1] - a[1] * b[0];
}

__global__ void wp_svd_kernel(const float* __restrict__ ws, float* __restrict__ out,
                              int B)
{
    const int b = blockIdx.x * blockDim.x + threadIdx.x;
    if (b >= B) return;

    float s16[16];
#pragma unroll
    for (int i = 0; i < 16; ++i) s16[i] = ws[(size_t)b * 16 + i];

    const double Sw = (double)s16[0];
    const double D = Sw + 1e-5;
    const double invD = 1.0 / D;
    double sc[3], tc[3];
#pragma unroll
    for (int i = 0; i < 3; ++i) {
        sc[i] = (double)s16[1 + i] * invD;
        tc[i] = (double)s16[4 + i] * invD;
    }
    const double f = 2.0 - Sw * invD;

    double H[3][3];
#pragma unroll
    for (int d = 0; d < 3; ++d)
#pragma unroll
        for (int e = 0; e < 3; ++e)
            H[d][e] = (double)s16[7 + 3 * d + e] * invD - sc[d] * tc[e] * f;

    // A = H^T H (symmetric PSD)
    double A[3][3];
#pragma unroll
    for (int i = 0; i < 3; ++i)
#pragma unroll
        for (int j = 0; j < 3; ++j)
            A[i][j] = H[0][i] * H[0][j] + H[1][i] * H[1][j] + H[2][i] * H[2][j];

    double V[3][3] = {{1, 0, 0}, {0, 1, 0}, {0, 0, 1}};
#pragma unroll
    for (int sweep = 0; sweep < 10; ++sweep) {
        jrot<0, 1>(A, V);
        jrot<0, 2>(A, V);
        jrot<1, 2>(A, V);
    }

    // sort eigenvalues descending
    const double l0 = A[0][0], l1 = A[1][1], l2 = A[2][2];
    int i0 = 0; double lm = l0;
    if (l1 > lm) { lm = l1; i0 = 1; }
    if (l2 > lm) { lm = l2; i0 = 2; }
    int i2 = 0; double ls = l0;
    if (l1 < ls) { ls = l1; i2 = 1; }
    if (l2 < ls) { ls = l2; i2 = 2; }
    if (i2 == i0) i2 = (i0 + 1) % 3;
    const int i1 = 3 - i0 - i2;

    double v1[3], v2[3], v3[3];
#pragma unroll
    for (int k = 0; k < 3; ++k) {
        v1[k] = V[k][i0];
        v2[k] = V[k][i1];
        v3[k] = V[k][i2];
    }

    // u1 = normalize(H v1); u2 = normalize(H v2 orthogonalized vs u1); u3 = u1 x u2
    double u1[3], u2[3], u3[3];
    matvec3(H, v1, u1);
    const double n1 = sqrt(dot3(u1, u1));
    const double inv1 = 1.0 / fmax(n1, 1e-300);
#pragma unroll
    for (int k = 0; k < 3; ++k) u1[k] *= inv1;

    matvec3(H, v2, u2);
    const double d12 = dot3(u2, u1);
#pragma unroll
    for (int k = 0; k < 3; ++k) u2[k] -= d12 * u1[k];
    double n2 = sqrt(dot3(u2, u2));
    if (n2 < 1e-14 * fmax(n1, 1e-300)) {
        // degenerate rank<=1: pick any vector orthogonal to u1
        double ax[3] = {1.0, 0.0, 0.0};
        if (fabs(u1[0]) > 0.9) { ax[0] = 0.0; ax[1] = 1.0; }
        cross3(u1, ax, u2);
        n2 = sqrt(dot3(u2, u2));
    }
    const double inv2 = 1.0 / fmax(n2, 1e-300);
#pragma unroll
    for (int k = 0; k < 3; ++k) u2[k] *= inv2;
    cross3(u1, u2, u3);

    // sign of det(V) folded into the v3 term:
    // R = v1 u1^T + v2 u2^T + sign(det V) * v3 u3^T
    double cr[3];
    cross3(v2, v3, cr);
    const double detV = dot3(v1, cr);
    const double s3 = (detV < 0.0) ? -1.0 : 1.0;

    double R[3][3];
#pragma unroll
    for (int i = 0; i < 3; ++i)
#pragma unroll
        for (int j = 0; j < 3; ++j)
            R[i][j] = v1[i] * u1[j] + v2[i] * u2[j] + s3 * v3[i] * u3[j];

    double t[3];
#pragma unroll
    for (int i = 0; i < 3; ++i)
        t[i] = tc[i] - (R[i][0] * sc[0] + R[i][1] * sc[1] + R[i][2] * sc[2]);

    float* outR = out + (size_t)b * 9;
#pragma unroll
    for (int i = 0; i < 3; ++i)
#pragma unroll
        for (int j = 0; j < 3; ++j)
            outR[3 * i + j] = (float)R[i][j];
    float* outT = out + (size_t)B * 9 + (size_t)b * 3;
#pragma unroll
    for (int i = 0; i < 3; ++i) outT[i] = (float)t[i];
}

extern "C" void kernel_launch(void* const* d_in, const int* in_sizes, int n_in,
                              void* d_out, int out_size, void* d_ws, size_t ws_size,
                              hipStream_t stream)
{
    const float* src = (const float*)d_in[0];
    const float* tgt = (const float*)d_in[1];
    const float* w   = (const float*)d_in[2];
    float* out = (float*)d_out;
    float* ws  = (float*)d_ws;
    const int B = in_sizes[2] / NPTS;  // 4096

    wp_reduce_kernel<<<B, THREADS, 0, stream>>>(src, tgt, w, ws);
    wp_svd_kernel<<<(B + 63) / 64, 64, 0, stream>>>(ws, out, B);
}

// Round 2
// 51.691 us; speedup vs baseline: 1.0083x; 1.0083x over previous
//
#include <hip/hip_runtime.h>
#include <math.h>

#define NPTS 2048
#define THREADS 256

// ---------------- Kernel 1: per-batch weighted reduction ----------------
// Per batch b, computes 16 sums over n:
//   [0] w  [1..3] w*src  [4..6] w*tgt  [7..15] w*src_d*tgt_e (row-major)
// w thresholded (w<0.5 -> 0), UNNORMALIZED.
// All global loads vectorized as float4 (16B/lane).
__global__ __launch_bounds__(THREADS) void wp_reduce_kernel(
    const float* __restrict__ src, const float* __restrict__ tgt,
    const float* __restrict__ w, float* __restrict__ ws)
{
    const int b = blockIdx.x;
    const int tid = threadIdx.x;
    const float* sp = src + (size_t)b * NPTS * 3;
    const float* tp = tgt + (size_t)b * NPTS * 3;
    const float* wp = w + (size_t)b * NPTS;

    float acc[16];
#pragma unroll
    for (int i = 0; i < 16; ++i) acc[i] = 0.f;

    // 2 iterations x 4 consecutive points per thread.
    // n0 = it*1024 + tid*4  -> w float4 aligned; src/tgt: 3 float4 each.
#pragma unroll
    for (int it = 0; it < NPTS / (THREADS * 4); ++it) {
        const int n0 = it * (THREADS * 4) + tid * 4;
        const float4 wq = *reinterpret_cast<const float4*>(wp + n0);
        const float4* s4 = reinterpret_cast<const float4*>(sp + 3 * n0);
        const float4 sa = s4[0], sb = s4[1], sc = s4[2];
        const float4* t4 = reinterpret_cast<const float4*>(tp + 3 * n0);
        const float4 ta = t4[0], tb = t4[1], tc = t4[2];

        const float wv[4]   = {wq.x, wq.y, wq.z, wq.w};
        const float sv[12]  = {sa.x, sa.y, sa.z, sa.w, sb.x, sb.y,
                               sb.z, sb.w, sc.x, sc.y, sc.z, sc.w};
        const float tv[12]  = {ta.x, ta.y, ta.z, ta.w, tb.x, tb.y,
                               tb.z, tb.w, tc.x, tc.y, tc.z, tc.w};

#pragma unroll
        for (int k = 0; k < 4; ++k) {
            const float wvk = (wv[k] < 0.5f) ? 0.f : wv[k];
            const float sx = sv[3 * k + 0];
            const float sy = sv[3 * k + 1];
            const float sz = sv[3 * k + 2];
            const float tx = tv[3 * k + 0];
            const float ty = tv[3 * k + 1];
            const float tz = tv[3 * k + 2];
            const float wsx = wvk * sx, wsy = wvk * sy, wsz = wvk * sz;
            acc[0] += wvk;
            acc[1] += wsx; acc[2] += wsy; acc[3] += wsz;
            acc[4] += wvk * tx; acc[5] += wvk * ty; acc[6] += wvk * tz;
            acc[7]  += wsx * tx; acc[8]  += wsx * ty; acc[9]  += wsx * tz;
            acc[10] += wsy * tx; acc[11] += wsy * ty; acc[12] += wsy * tz;
            acc[13] += wsz * tx; acc[14] += wsz * ty; acc[15] += wsz * tz;
        }
    }

    // 64-lane wave butterfly reduction of all 16 accumulators
#pragma unroll
    for (int off = 32; off >= 1; off >>= 1) {
#pragma unroll
        for (int i = 0; i < 16; ++i)
            acc[i] += __shfl_xor(acc[i], off, 64);
    }

    __shared__ float lds[4][16];
    const int wave = tid >> 6;
    const int lane = tid & 63;
    if (lane == 0) {
#pragma unroll
        for (int i = 0; i < 16; ++i) lds[wave][i] = acc[i];
    }
    __syncthreads();
    if (tid < 16) {
        const float v = lds[0][tid] + lds[1][tid] + lds[2][tid] + lds[3][tid];
        ws[(size_t)b * 16 + tid] = v;
    }
}

// ---------------- Kernel 2: per-batch 3x3 Kabsch (fp64 Jacobi SVD) ----------------

template <int P, int Q>
__device__ inline void jrot(double A[3][3], double V[3][3])
{
    const double apq = A[P][Q];
    if (fabs(apq) < 1e-300) return;
    const double theta = (A[Q][Q] - A[P][P]) / (2.0 * apq);
    const double t = ((theta >= 0.0) ? 1.0 : -1.0) /
                     (fabs(theta) + sqrt(theta * theta + 1.0));
    const double c = 1.0 / sqrt(t * t + 1.0);
    const double s = t * c;
#pragma unroll
    for (int k = 0; k < 3; ++k) {
        const double akp = A[k][P], akq = A[k][Q];
        A[k][P] = c * akp - s * akq;
        A[k][Q] = s * akp + c * akq;
    }
#pragma unroll
    for (int k = 0; k < 3; ++k) {
        const double apk = A[P][k], aqk = A[Q][k];
        A[P][k] = c * apk - s * aqk;
        A[Q][k] = s * apk + c * aqk;
    }
#pragma unroll
    for (int k = 0; k < 3; ++k) {
        const double vkp = V[k][P], vkq = V[k][Q];
        V[k][P] = c * vkp - s * vkq;
        V[k][Q] = s * vkp + c * vkq;
    }
}

__device__ inline void matvec3(const double H[3][3], const double v[3], double u[3])
{
#pragma unroll
    for (int i = 0; i < 3; ++i)
        u[i] = H[i][0] * v[0] + H[i][1] * v[1] + H[i][2] * v[2];
}

__device__ inline double dot3(const double a[3], const double b[3])
{
    return a[0] * b[0] + a[1] * b[1] + a[2] * b[2];
}

__device__ inline void cross3(const double a[3], const double b[3], double c[3])
{
    c[0] = a[1] * b[2] - a[2] * b[1];
    c[1] = a[2] * b[0] - a[0] * b[2];
    c[2] = a[0] * b[1] - a[1] * b[0];
}

__global__ void wp_svd_kernel(const float* __restrict__ ws, float* __restrict__ out,
                              int B)
{
    const int b = blockIdx.x * blockDim.x + threadIdx.x;
    if (b >= B) return;

    float s16[16];
#pragma unroll
    for (int i = 0; i < 16; ++i) s16[i] = ws[(size_t)b * 16 + i];

    const double Sw = (double)s16[0];
    const double D = Sw + 1e-5;
    const double invD = 1.0 / D;
    double sc[3], tc[3];
#pragma unroll
    for (int i = 0; i < 3; ++i) {
        sc[i] = (double)s16[1 + i] * invD;
        tc[i] = (double)s16[4 + i] * invD;
    }
    const double f = 2.0 - Sw * invD;

    double H[3][3];
#pragma unroll
    for (int d = 0; d < 3; ++d)
#pragma unroll
        for (int e = 0; e < 3; ++e)
            H[d][e] = (double)s16[7 + 3 * d + e] * invD - sc[d] * tc[e] * f;

    // A = H^T H (symmetric PSD)
    double A[3][3];
#pragma unroll
    for (int i = 0; i < 3; ++i)
#pragma unroll
        for (int j = 0; j < 3; ++j)
            A[i][j] = H[0][i] * H[0][j] + H[1][i] * H[1][j] + H[2][i] * H[2][j];

    double V[3][3] = {{1, 0, 0}, {0, 1, 0}, {0, 0, 1}};
#pragma unroll
    for (int sweep = 0; sweep < 10; ++sweep) {
        jrot<0, 1>(A, V);
        jrot<0, 2>(A, V);
        jrot<1, 2>(A, V);
    }

    // sort eigenvalues descending
    const double l0 = A[0][0], l1 = A[1][1], l2 = A[2][2];
    int i0 = 0; double lm = l0;
    if (l1 > lm) { lm = l1; i0 = 1; }
    if (l2 > lm) { lm = l2; i0 = 2; }
    int i2 = 0; double ls = l0;
    if (l1 < ls) { ls = l1; i2 = 1; }
    if (l2 < ls) { ls = l2; i2 = 2; }
    if (i2 == i0) i2 = (i0 + 1) % 3;
    const int i1 = 3 - i0 - i2;

    double v1[3], v2[3], v3[3];
#pragma unroll
    for (int k = 0; k < 3; ++k) {
        v1[k] = V[k][i0];
        v2[k] = V[k][i1];
        v3[k] = V[k][i2];
    }

    // u1 = normalize(H v1); u2 = normalize(H v2 orth. vs u1); u3 = u1 x u2
    double u1[3], u2[3], u3[3];
    matvec3(H, v1, u1);
    const double n1 = sqrt(dot3(u1, u1));
    const double inv1 = 1.0 / fmax(n1, 1e-300);
#pragma unroll
    for (int k = 0; k < 3; ++k) u1[k] *= inv1;

    matvec3(H, v2, u2);
    const double d12 = dot3(u2, u1);
#pragma unroll
    for (int k = 0; k < 3; ++k) u2[k] -= d12 * u1[k];
    double n2 = sqrt(dot3(u2, u2));
    if (n2 < 1e-14 * fmax(n1, 1e-300)) {
        // degenerate rank<=1: pick any vector orthogonal to u1
        double ax[3] = {1.0, 0.0, 0.0};
        if (fabs(u1[0]) > 0.9) { ax[0] = 0.0; ax[1] = 1.0; }
        cross3(u1, ax, u2);
        n2 = sqrt(dot3(u2, u2));
    }
    const double inv2 = 1.0 / fmax(n2, 1e-300);
#pragma unroll
    for (int k = 0; k < 3; ++k) u2[k] *= inv2;
    cross3(u1, u2, u3);

    // R = v1 u1^T + v2 u2^T + sign(det V) * v3 u3^T
    double cr[3];
    cross3(v2, v3, cr);
    const double detV = dot3(v1, cr);
    const double s3 = (detV < 0.0) ? -1.0 : 1.0;

    double R[3][3];
#pragma unroll
    for (int i = 0; i < 3; ++i)
#pragma unroll
        for (int j = 0; j < 3; ++j)
            R[i][j] = v1[i] * u1[j] + v2[i] * u2[j] + s3 * v3[i] * u3[j];

    double t[3];
#pragma unroll
    for (int i = 0; i < 3; ++i)
        t[i] = tc[i] - (R[i][0] * sc[0] + R[i][1] * sc[1] + R[i][2] * sc[2]);

    float* outR = out + (size_t)b * 9;
#pragma unroll
    for (int i = 0; i < 3; ++i)
#pragma unroll
        for (int j = 0; j < 3; ++j)
            outR[3 * i + j] = (float)R[i][j];
    float* outT = out + (size_t)B * 9 + (size_t)b * 3;
#pragma unroll
    for (int i = 0; i < 3; ++i) outT[i] = (float)t[i];
}

extern "C" void kernel_launch(void* const* d_in, const int* in_sizes, int n_in,
                              void* d_out, int out_size, void* d_ws, size_t ws_size,
                              hipStream_t stream)
{
    const float* src = (const float*)d_in[0];
    const float* tgt = (const float*)d_in[1];
    const float* w   = (const float*)d_in[2];
    float* out = (float*)d_out;
    float* ws  = (float*)d_ws;
    const int B = in_sizes[2] / NPTS;  // 4096

    wp_reduce_kernel<<<B, THREADS, 0, stream>>>(src, tgt, w, ws);
    wp_svd_kernel<<<(B + 63) / 64, 64, 0, stream>>>(ws, out, B);
}

// Round 3
// 48.907 us; speedup vs baseline: 1.0657x; 1.0569x over previous
//
#include <hip/hip_runtime.h>
#include <math.h>

#define NPTS 2048
#define T1 64                       // one wave per block
#define ITERS (NPTS / (T1 * 4))     // 8 iterations of 4 points/thread

// ---------------- Kernel 1: per-batch weighted reduction ----------------
// Per batch b, 16 sums over n:
//   [0] w  [1..3] w*src  [4..6] w*tgt  [7..15] w*src_d*tgt_e (row-major)
// w thresholded (w<0.5 -> 0), UNNORMALIZED.
// One wave per batch; register double-buffered float4 loads (keeps ~14
// loads in flight); transposed butterfly reduce (17 shuffles, not 96).

struct Pts { float4 wq, s0, s1, s2, t0, t1, t2; };

__device__ inline void loadPts(Pts& p, const float* __restrict__ wp,
                               const float* __restrict__ sp,
                               const float* __restrict__ tp, int n0)
{
    p.wq = *reinterpret_cast<const float4*>(wp + n0);
    const float4* s4 = reinterpret_cast<const float4*>(sp + 3 * n0);
    p.s0 = s4[0]; p.s1 = s4[1]; p.s2 = s4[2];
    const float4* t4 = reinterpret_cast<const float4*>(tp + 3 * n0);
    p.t0 = t4[0]; p.t1 = t4[1]; p.t2 = t4[2];
}

__device__ inline void accPts(const Pts& p, float acc[16])
{
    const float wv[4]  = {p.wq.x, p.wq.y, p.wq.z, p.wq.w};
    const float sv[12] = {p.s0.x, p.s0.y, p.s0.z, p.s0.w,
                          p.s1.x, p.s1.y, p.s1.z, p.s1.w,
                          p.s2.x, p.s2.y, p.s2.z, p.s2.w};
    const float tv[12] = {p.t0.x, p.t0.y, p.t0.z, p.t0.w,
                          p.t1.x, p.t1.y, p.t1.z, p.t1.w,
                          p.t2.x, p.t2.y, p.t2.z, p.t2.w};
#pragma unroll
    for (int k = 0; k < 4; ++k) {
        const float wvk = (wv[k] < 0.5f) ? 0.f : wv[k];
        const float sx = sv[3 * k + 0], sy = sv[3 * k + 1], sz = sv[3 * k + 2];
        const float tx = tv[3 * k + 0], ty = tv[3 * k + 1], tz = tv[3 * k + 2];
        const float wsx = wvk * sx, wsy = wvk * sy, wsz = wvk * sz;
        acc[0] += wvk;
        acc[1] += wsx; acc[2] += wsy; acc[3] += wsz;
        acc[4] += wvk * tx; acc[5] += wvk * ty; acc[6] += wvk * tz;
        acc[7]  += wsx * tx; acc[8]  += wsx * ty; acc[9]  += wsx * tz;
        acc[10] += wsy * tx; acc[11] += wsy * ty; acc[12] += wsy * tz;
        acc[13] += wsz * tx; acc[14] += wsz * ty; acc[15] += wsz * tz;
    }
}

// One transposed-butterfly level: halves the live accumulator count.
// Lanes with (lane & M) keep the high half, others the low half; each
// side receives the half it keeps from its XOR-partner and adds.
template <int M, int HALF>
__device__ inline void bflevel(float acc[16], int lane)
{
    const bool hi = lane & M;
#pragma unroll
    for (int j = 0; j < HALF; ++j) {
        const float keep = hi ? acc[j + HALF] : acc[j];
        const float send = hi ? acc[j] : acc[j + HALF];
        acc[j] = keep + __shfl_xor(send, M, 64);
    }
}

__global__ __launch_bounds__(T1, 4) void wp_reduce_kernel(
    const float* __restrict__ src, const float* __restrict__ tgt,
    const float* __restrict__ w, float* __restrict__ ws)
{
    const int b = blockIdx.x;
    const int lane = threadIdx.x;
    const float* sp = src + (size_t)b * NPTS * 3;
    const float* tp = tgt + (size_t)b * NPTS * 3;
    const float* wp = w + (size_t)b * NPTS;

    float acc[16];
#pragma unroll
    for (int i = 0; i < 16; ++i) acc[i] = 0.f;

    Pts A, B;
    loadPts(A, wp, sp, tp, lane * 4);
#pragma unroll
    for (int it = 0; it < ITERS; ++it) {
        const int n_next = (it + 1) * (T1 * 4) + lane * 4;
        if (it & 1) {
            if (it + 1 < ITERS) loadPts(A, wp, sp, tp, n_next);
            accPts(B, acc);
        } else {
            if (it + 1 < ITERS) loadPts(B, wp, sp, tp, n_next);
            accPts(A, acc);
        }
    }

    // Transposed butterfly: 8+4+2+1 shuffles, then 2 single-value levels.
    bflevel<1, 8>(acc, lane);
    bflevel<2, 4>(acc, lane);
    bflevel<4, 2>(acc, lane);
    bflevel<8, 1>(acc, lane);
    acc[0] += __shfl_xor(acc[0], 16, 64);
    acc[0] += __shfl_xor(acc[0], 32, 64);

    // lane L (L<16) holds the total for original index bitrev4(L)
    if (lane < 16) {
        const int idx = ((lane & 1) << 3) | ((lane & 2) << 1) |
                        ((lane & 4) >> 1) | ((lane & 8) >> 3);
        ws[(size_t)b * 16 + idx] = acc[0];
    }
}

// ---------------- Kernel 2: per-batch 3x3 Kabsch (fp64 Jacobi SVD) ----------------

template <int P, int Q>
__device__ inline void jrot(double A[3][3], double V[3][3])
{
    const double apq = A[P][Q];
    if (fabs(apq) < 1e-300) return;
    const double theta = (A[Q][Q] - A[P][P]) / (2.0 * apq);
    const double t = ((theta >= 0.0) ? 1.0 : -1.0) /
                     (fabs(theta) + sqrt(theta * theta + 1.0));
    const double c = 1.0 / sqrt(t * t + 1.0);
    const double s = t * c;
#pragma unroll
    for (int k = 0; k < 3; ++k) {
        const double akp = A[k][P], akq = A[k][Q];
        A[k][P] = c * akp - s * akq;
        A[k][Q] = s * akp + c * akq;
    }
#pragma unroll
    for (int k = 0; k < 3; ++k) {
        const double apk = A[P][k], aqk = A[Q][k];
        A[P][k] = c * apk - s * aqk;
        A[Q][k] = s * apk + c * aqk;
    }
#pragma unroll
    for (int k = 0; k < 3; ++k) {
        const double vkp = V[k][P], vkq = V[k][Q];
        V[k][P] = c * vkp - s * vkq;
        V[k][Q] = s * vkp + c * vkq;
    }
}

__device__ inline void matvec3(const double H[3][3], const double v[3], double u[3])
{
#pragma unroll
    for (int i = 0; i < 3; ++i)
        u[i] = H[i][0] * v[0] + H[i][1] * v[1] + H[i][2] * v[2];
}

__device__ inline double dot3(const double a[3], const double b[3])
{
    return a[0] * b[0] + a[1] * b[1] + a[2] * b[2];
}

__device__ inline void cross3(const double a[3], const double b[3], double c[3])
{
    c[0] = a[1] * b[2] - a[2] * b[1];
    c[1] = a[2] * b[0] - a[0] * b[2];
    c[2] = a[0] * b[1] - a[1] * b[0];
}

__global__ void wp_svd_kernel(const float* __restrict__ ws, float* __restrict__ out,
                              int B)
{
    const int b = blockIdx.x * blockDim.x + threadIdx.x;
    if (b >= B) return;

    float s16[16];
#pragma unroll
    for (int i = 0; i < 16; ++i) s16[i] = ws[(size_t)b * 16 + i];

    const double Sw = (double)s16[0];
    const double D = Sw + 1e-5;
    const double invD = 1.0 / D;
    double sc[3], tc[3];
#pragma unroll
    for (int i = 0; i < 3; ++i) {
        sc[i] = (double)s16[1 + i] * invD;
        tc[i] = (double)s16[4 + i] * invD;
    }
    const double f = 2.0 - Sw * invD;

    double H[3][3];
#pragma unroll
    for (int d = 0; d < 3; ++d)
#pragma unroll
        for (int e = 0; e < 3; ++e)
            H[d][e] = (double)s16[7 + 3 * d + e] * invD - sc[d] * tc[e] * f;

    // A = H^T H (symmetric PSD)
    double A[3][3];
#pragma unroll
    for (int i = 0; i < 3; ++i)
#pragma unroll
        for (int j = 0; j < 3; ++j)
            A[i][j] = H[0][i] * H[0][j] + H[1][i] * H[1][j] + H[2][i] * H[2][j];

    double V[3][3] = {{1, 0, 0}, {0, 1, 0}, {0, 0, 1}};
#pragma unroll
    for (int sweep = 0; sweep < 10; ++sweep) {
        jrot<0, 1>(A, V);
        jrot<0, 2>(A, V);
        jrot<1, 2>(A, V);
    }

    // sort eigenvalues descending
    const double l0 = A[0][0], l1 = A[1][1], l2 = A[2][2];
    int i0 = 0; double lm = l0;
    if (l1 > lm) { lm = l1; i0 = 1; }
    if (l2 > lm) { lm = l2; i0 = 2; }
    int i2 = 0; double ls = l0;
    if (l1 < ls) { ls = l1; i2 = 1; }
    if (l2 < ls) { ls = l2; i2 = 2; }
    if (i2 == i0) i2 = (i0 + 1) % 3;
    const int i1 = 3 - i0 - i2;

    double v1[3], v2[3], v3[3];
#pragma unroll
    for (int k = 0; k < 3; ++k) {
        v1[k] = V[k][i0];
        v2[k] = V[k][i1];
        v3[k] = V[k][i2];
    }

    // u1 = normalize(H v1); u2 = normalize(H v2 orth. vs u1); u3 = u1 x u2
    double u1[3], u2[3], u3[3];
    matvec3(H, v1, u1);
    const double n1 = sqrt(dot3(u1, u1));
    const double inv1 = 1.0 / fmax(n1, 1e-300);
#pragma unroll
    for (int k = 0; k < 3; ++k) u1[k] *= inv1;

    matvec3(H, v2, u2);
    const double d12 = dot3(u2, u1);
#pragma unroll
    for (int k = 0; k < 3; ++k) u2[k] -= d12 * u1[k];
    double n2 = sqrt(dot3(u2, u2));
    if (n2 < 1e-14 * fmax(n1, 1e-300)) {
        // degenerate rank<=1: pick any vector orthogonal to u1
        double ax[3] = {1.0, 0.0, 0.0};
        if (fabs(u1[0]) > 0.9) { ax[0] = 0.0; ax[1] = 1.0; }
        cross3(u1, ax, u2);
        n2 = sqrt(dot3(u2, u2));
    }
    const double inv2 = 1.0 / fmax(n2, 1e-300);
#pragma unroll
    for (int k = 0; k < 3; ++k) u2[k] *= inv2;
    cross3(u1, u2, u3);

    // R = v1 u1^T + v2 u2^T + sign(det V) * v3 u3^T
    double cr[3];
    cross3(v2, v3, cr);
    const double detV = dot3(v1, cr);
    const double s3 = (detV < 0.0) ? -1.0 : 1.0;

    double R[3][3];
#pragma unroll
    for (int i = 0; i < 3; ++i)
#pragma unroll
        for (int j = 0; j < 3; ++j)
            R[i][j] = v1[i] * u1[j] + v2[i] * u2[j] + s3 * v3[i] * u3[j];

    double t[3];
#pragma unroll
    for (int i = 0; i < 3; ++i)
        t[i] = tc[i] - (R[i][0] * sc[0] + R[i][1] * sc[1] + R[i][2] * sc[2]);

    float* outR = out + (size_t)b * 9;
#pragma unroll
    for (int i = 0; i < 3; ++i)
#pragma unroll
        for (int j = 0; j < 3; ++j)
            outR[3 * i + j] = (float)R[i][j];
    float* outT = out + (size_t)B * 9 + (size_t)b * 3;
#pragma unroll
    for (int i = 0; i < 3; ++i) outT[i] = (float)t[i];
}

extern "C" void kernel_launch(void* const* d_in, const int* in_sizes, int n_in,
                              void* d_out, int out_size, void* d_ws, size_t ws_size,
                              hipStream_t stream)
{
    const float* src = (const float*)d_in[0];
    const float* tgt = (const float*)d_in[1];
    const float* w   = (const float*)d_in[2];
    float* out = (float*)d_out;
    float* ws  = (float*)d_ws;
    const int B = in_sizes[2] / NPTS;  // 4096

    wp_reduce_kernel<<<B, T1, 0, stream>>>(src, tgt, w, ws);
    wp_svd_kernel<<<(B + 63) / 64, 64, 0, stream>>>(ws, out, B);
}